// Round 8
// baseline (171.438 us; speedup 1.0000x reference)
//
#include <hip/hip_runtime.h>
#include <hip/hip_bf16.h>

// B=8, S=128, E=50, D=300, DE=50 — ALL I/O FLOAT32.
// out: node[307200] | edge[6553600].
// ws (floats): R1[51200] | R2[51200] | M[131072]

typedef __bf16 bf16x8 __attribute__((ext_vector_type(8)));
typedef float f32x4 __attribute__((ext_vector_type(4)));

__device__ __forceinline__ unsigned short f2bf(float f) {
    __hip_bfloat16 h = __float2bfloat16(f);
    union { __hip_bfloat16 h; unsigned short u; } c; c.h = h; return c.u;
}

// ---------------- K0: M[b,i,j] = mean_e(wps) + (i==j) — pure streaming ---------
__global__ void __launch_bounds__(256) k_msum(
    const float* __restrict__ wps, float* __restrict__ M)
{
    int gid = blockIdx.x * 256 + threadIdx.x;      // [0, 131072)
    const float2* p = (const float2*)(wps + (size_t)gid * 50);
    float s = 0.f;
#pragma unroll
    for (int n = 0; n < 25; ++n) { float2 v = p[n]; s += v.x + v.y; }
    int i = (gid >> 7) & 127, j = gid & 127;
    M[gid] = s * (1.0f / 50.0f) + ((i == j) ? 1.0f : 0.0f);
}

// ---------------- K1: per-row  Axm=M@x ; h=Axm@Ww+Wb ; LN ; relu ; R1/R2 -------
// one block per row (b*128+i); 256 threads; ~4.5 KB LDS -> ~8 blocks/CU.
__global__ void __launch_bounds__(256) k_node(
    const float* __restrict__ M,
    const float* __restrict__ wa,
    const float* __restrict__ x,
    const float* __restrict__ Ww,
    const float* __restrict__ Wb,
    const float* __restrict__ lna,
    const float* __restrict__ lnb,
    const float* __restrict__ Rw,
    const float* __restrict__ rb,
    float* __restrict__ node_out,
    float* __restrict__ R1, float* __restrict__ R2)
{
    __shared__ __align__(16) float Ml[128];
    __shared__ __align__(16) float axm[304];
    __shared__ float srcL[352];                   // [diag(50) | node(300)]
    __shared__ float p1s[5][50], p2s[5][50];
    __shared__ float red[8];
    __shared__ float stats[2];
    int tid = threadIdx.x;
    int row = blockIdx.x;                  // b*128 + i
    int b = row >> 7, i = row & 127;

    // ---- load M row (512 B) + diag(wa) ----
    if (tid < 128) Ml[tid] = M[(size_t)row * 128 + tid];
    else if (tid >= 128 && tid < 178) srcL[tid - 128] = wa[((size_t)row * 128 + i) * 50 + (tid - 128)];
    __syncthreads();

    // ---- Axm[d] = sum_j Ml[j] * x[b,j,d]   (x[b] L2-resident, 150 KB) ----
    int d0 = tid;
    bool has2 = (tid < 44);
    int d1 = has2 ? 256 + tid : 299;
    {
        float a0 = 0.f, a1 = 0.f;
        const float* xp = x + (size_t)b * 38400;
#pragma unroll 16
        for (int j = 0; j < 128; ++j) {
            float m = Ml[j];
            a0 += m * xp[j * 300 + d0];
            a1 += m * xp[j * 300 + d1];
        }
        axm[d0] = a0;
        if (has2) axm[d1] = a1;
    }
    __syncthreads();

    // ---- h[d] = Wb[d] + sum_k axm[k] * Ww[k,d]   (Ww L2-resident, 360 KB) ----
    float h0 = Wb[d0];
    float h1 = Wb[d1];
    {
        const float* wp0 = Ww + d0;
        const float* wp1 = Ww + d1;
        const f32x4* a4 = (const f32x4*)axm;
#pragma unroll 5
        for (int k4 = 0; k4 < 75; ++k4) {
            f32x4 av = a4[k4];
            int k = k4 * 4;
            h0 += av[0] * wp0[(k + 0) * 300];
            h0 += av[1] * wp0[(k + 1) * 300];
            h0 += av[2] * wp0[(k + 2) * 300];
            h0 += av[3] * wp0[(k + 3) * 300];
            h1 += av[0] * wp1[(k + 0) * 300];
            h1 += av[1] * wp1[(k + 1) * 300];
            h1 += av[2] * wp1[(k + 2) * 300];
            h1 += av[3] * wp1[(k + 3) * 300];
        }
    }

    // ---- LN stats over 300 (register + shuffle reduce) ----
    {
        float s1 = h0 + (has2 ? h1 : 0.f);
        float s2 = h0 * h0 + (has2 ? h1 * h1 : 0.f);
        for (int off = 32; off > 0; off >>= 1) {
            s1 += __shfl_down(s1, off);
            s2 += __shfl_down(s2, off);
        }
        int wv = tid >> 6, lane = tid & 63;
        if (lane == 0) { red[wv] = s1; red[4 + wv] = s2; }
    }
    __syncthreads();
    if (tid == 0) {
        float s1 = red[0] + red[1] + red[2] + red[3];
        float s2 = red[4] + red[5] + red[6] + red[7];
        float mean = s1 * (1.0f / 300.0f);
        float var = (s2 - 300.0f * mean * mean) * (1.0f / 299.0f);
        var = fmaxf(var, 0.0f);
        stats[0] = mean;
        stats[1] = 1.0f / (sqrtf(var) + 1e-6f);
    }
    __syncthreads();

    // ---- node = relu(LN(h)) -> global + srcL ----
    {
        float mean = stats[0], inv = stats[1];
        float n0 = fmaxf(lna[d0] * (h0 - mean) * inv + lnb[d0], 0.f);
        node_out[(size_t)row * 300 + d0] = n0;
        srcL[50 + d0] = n0;
        if (has2) {
            float n1 = fmaxf(lna[d1] * (h1 - mean) * inv + lnb[d1], 0.f);
            node_out[(size_t)row * 300 + d1] = n1;
            srcL[50 + d1] = n1;
        }
    }
    __syncthreads();

    // ---- R1/R2: split-K x5 over src=[diag|node] (Rw L2-resident, 150 KB) ----
    if (tid < 250) {
        int p = tid / 50, k = tid % 50;
        int srcOff, w1b, w2b, len;
        if (p == 0) { srcOff = 0;  w1b = 50 * 50;  w2b = 100 * 50; len = 50; }
        else {
            int dd = (p - 1) * 75;
            srcOff = 50 + dd; w1b = (150 + dd) * 50; w2b = (450 + dd) * 50; len = 75;
        }
        float r1 = 0.f, r2 = 0.f;
        const float* w1p = Rw + w1b + k;
        const float* w2p = Rw + w2b + k;
#pragma unroll 5
        for (int t = 0; t < len; ++t) {
            float sv = srcL[srcOff + t];
            r1 += sv * w1p[t * 50];
            r2 += sv * w2p[t * 50];
        }
        p1s[p][k] = r1; p2s[p][k] = r2;
    }
    __syncthreads();
    if (tid < 50) {
        float s1 = 0.f, s2 = rb[tid];
#pragma unroll
        for (int p = 0; p < 5; ++p) { s1 += p1s[p][tid]; s2 += p2s[p][tid]; }
        R1[(size_t)row * 50 + tid] = s1;
        R2[(size_t)row * 50 + tid] = s2;
    }
}

// ---------------- K2: edge_out = wa·Rw[0:50] (MFMA) + R1[j] + R2[i] ------------
__global__ void __launch_bounds__(256) k_edge(
    const float* __restrict__ wa,
    const float* __restrict__ Rw,
    const float* __restrict__ R1, const float* __restrict__ R2,
    float* __restrict__ eout)
{
    __shared__ __align__(16) unsigned char smem[27648];
    unsigned short* waA  = (unsigned short*)smem;            // 128*72 bf16
    unsigned short* rwBT = (unsigned short*)(smem + 18432);  // 64*72 bf16
    float* outF = (float*)smem;                              // alias: 6400 floats
    int tid = threadIdx.x;
    int bi = blockIdx.x;       // b*128 + i
    int b = bi >> 7;

    for (int idx = tid; idx < 2304; idx += 256) ((unsigned int*)rwBT)[idx] = 0u;
    for (int idx = tid; idx < 1408; idx += 256) {            // zero waA pad e in [50,72)
        int j = idx / 11, c = idx % 11;
        *((unsigned int*)(waA + j * 72 + 50) + c) = 0u;
    }
    __syncthreads();

    const float2* wap = (const float2*)(wa + (size_t)bi * 6400);
    for (int idx = tid; idx < 3200; idx += 256) {
        float2 v = wap[idx];
        int f = idx * 2;
        int j = f / 50, e = f % 50;
        unsigned int pack = (unsigned int)f2bf(v.x) | ((unsigned int)f2bf(v.y) << 16);
        *(unsigned int*)(waA + j * 72 + e) = pack;
    }
    for (int idx = tid; idx < 2500; idx += 256) {            // transpose+cvt Rw[0:50][0:50]
        int e = idx / 50, kk = idx % 50;
        rwBT[kk * 72 + e] = f2bf(Rw[idx]);
    }
    __syncthreads();

    int lane = tid & 63, wv = tid >> 6;
    int q = lane >> 4, lr = lane & 15;
    f32x4 acc[2][4] = {};

#pragma unroll
    for (int ks = 0; ks < 2; ++ks) {
        int e0 = ks * 32 + q * 8;
        bf16x8 a0 = *(const bf16x8*)&waA[(wv * 32 + lr) * 72 + e0];
        bf16x8 a1 = *(const bf16x8*)&waA[(wv * 32 + 16 + lr) * 72 + e0];
#pragma unroll
        for (int nt = 0; nt < 4; ++nt) {
            bf16x8 bb = *(const bf16x8*)&rwBT[(nt * 16 + lr) * 72 + e0];
            acc[0][nt] = __builtin_amdgcn_mfma_f32_16x16x32_bf16(a0, bb, acc[0][nt], 0, 0, 0);
            acc[1][nt] = __builtin_amdgcn_mfma_f32_16x16x32_bf16(a1, bb, acc[1][nt], 0, 0, 0);
        }
    }
    __syncthreads();   // staging LDS dead; alias as outF

    const float* r2p = R2 + (size_t)bi * 50;
#pragma unroll
    for (int nt = 0; nt < 4; ++nt) {
        int kk = nt * 16 + lr;
        if (kk < 50) {
            float r2v = r2p[kk];
#pragma unroll
            for (int mi = 0; mi < 2; ++mi) {
                int jbase = wv * 32 + mi * 16 + q * 4;
#pragma unroll
                for (int r = 0; r < 4; ++r)
                    outF[(jbase + r) * 50 + kk] = acc[mi][nt][r] + r2v;
            }
        }
    }
    __syncthreads();

    const float4* R1b = (const float4*)(R1 + (size_t)b * 6400);
    const float4* L4  = (const float4*)outF;
    float4* op4 = (float4*)(eout + (size_t)bi * 6400);
    for (int f4 = tid; f4 < 1600; f4 += 256) {
        float4 v = L4[f4];
        float4 r = R1b[f4];
        v.x += r.x; v.y += r.y; v.z += r.z; v.w += r.w;
        op4[f4] = v;
    }
}

extern "C" void kernel_launch(void* const* d_in, const int* in_sizes, int n_in,
                              void* d_out, int out_size, void* d_ws, size_t ws_size,
                              hipStream_t stream)
{
    const float* wps = (const float*)d_in[0];
    const float* wa  = (const float*)d_in[1];
    const float* x   = (const float*)d_in[2];
    // d_in[3] self_loop: identity on every channel, folded into k_msum (+1 on diag)
    const float* Ww  = (const float*)d_in[4];
    const float* Wb  = (const float*)d_in[5];
    const float* lna = (const float*)d_in[6];
    const float* lnb = (const float*)d_in[7];
    const float* Rw  = (const float*)d_in[8];
    const float* rb  = (const float*)d_in[9];

    float* R1 = (float*)d_ws;                    // 51200 floats
    float* R2 = ((float*)d_ws) + 51200;          // 51200 floats
    float* M  = ((float*)d_ws) + 102400;         // 131072 floats

    float* node_out = (float*)d_out;             // 307200 floats
    float* edge_out = node_out + 307200;         // 6553600 floats

    k_msum<<<512, 256, 0, stream>>>(wps, M);
    k_node<<<1024, 256, 0, stream>>>(M, wa, x, Ww, Wb, lna, lnb, Rw, rb,
                                     node_out, R1, R2);
    k_edge<<<1024, 256, 0, stream>>>(wa, Rw, R1, R2, edge_out);
}

// Round 9
// 151.778 us; speedup vs baseline: 1.1295x; 1.1295x over previous
//
#include <hip/hip_runtime.h>
#include <hip/hip_bf16.h>

// B=8, S=128, E=50, D=300, DE=50 — ALL I/O FLOAT32.
// out: node[307200] | edge[6553600].
// ws (floats): R1[51200] | R2[51200] | M[131072]

typedef __bf16 bf16x8 __attribute__((ext_vector_type(8)));
typedef float f32x4 __attribute__((ext_vector_type(4)));

__device__ __forceinline__ unsigned short f2bf(float f) {
    __hip_bfloat16 h = __float2bfloat16(f);
    union { __hip_bfloat16 h; unsigned short u; } c; c.h = h; return c.u;
}

// ---------------- K0: M[b,i,j] = mean_e(wps) + (i==j) — pure streaming ---------
__global__ void __launch_bounds__(256) k_msum(
    const float* __restrict__ wps, float* __restrict__ M)
{
    int gid = blockIdx.x * 256 + threadIdx.x;      // [0, 131072)
    const float2* p = (const float2*)(wps + (size_t)gid * 50);
    float s = 0.f;
#pragma unroll
    for (int n = 0; n < 25; ++n) { float2 v = p[n]; s += v.x + v.y; }
    int i = (gid >> 7) & 127, j = gid & 127;
    M[gid] = s * (1.0f / 50.0f) + ((i == j) ? 1.0f : 0.0f);
}

// ---------------- K1: 4 rows/block, 1024 thr, split-K x4 groups ----------------
// Axm=M@x ; h=Axm@Ww+Wb ; LN(unbiased+eps) ; relu ; R1/R2. Shared operands
// (x, Ww, Rw) read ONCE per block -> 4x less L2 traffic than per-row blocks.
__global__ void __launch_bounds__(1024) k_node(
    const float* __restrict__ M,
    const float* __restrict__ wa,
    const float* __restrict__ x,
    const float* __restrict__ Ww,
    const float* __restrict__ Wb,
    const float* __restrict__ lna,
    const float* __restrict__ lnb,
    const float* __restrict__ Rw,
    const float* __restrict__ rb,
    float* __restrict__ node_out,
    float* __restrict__ R1, float* __restrict__ R2)
{
    __shared__ __align__(16) float axp[4864];   // partials: axm/h (d*16+g*4+r), then q1|q2
    __shared__ __align__(16) float axm4[1216];  // axm[304][4] (row-vec4 per k)
    __shared__ __align__(16) float Mlt[512];    // M[j][4 rows]
    __shared__ __align__(16) float srcL[1408];  // [diag(50)|node(300)+pad][4]
    __shared__ float red1[20], red2[20], stats[8];

    int tid = threadIdx.x;
    int g = tid >> 8, t = tid & 255;
    int row0 = blockIdx.x * 4;
    int b = row0 >> 7, i0 = row0 & 127;

    // ---- phase 0: M rows + diag(wa) ----
    if (tid < 512) {
        int r = tid >> 7, j = tid & 127;
        Mlt[j * 4 + r] = M[(size_t)(row0 + r) * 128 + j];
    } else if (tid < 712) {
        int idx = tid - 512, r = idx / 50, e = idx % 50;
        srcL[e * 4 + r] = wa[((size_t)(row0 + r) * 128 + (i0 + r)) * 50 + e];
    }
    __syncthreads();

    int d0 = t;
    bool has2 = (t < 44);
    int d1 = has2 ? 256 + t : 299;

    // ---- phase 1: Axm partials, group g covers j in [32g, 32g+32) ----
    {
        f32x4 a0 = {0.f, 0.f, 0.f, 0.f}, a1 = {0.f, 0.f, 0.f, 0.f};
        const float* xp = x + (size_t)b * 38400;
        int j0 = g * 32;
#pragma unroll 8
        for (int jj = 0; jj < 32; ++jj) {
            int j = j0 + jj;
            f32x4 m4 = *(const f32x4*)&Mlt[j * 4];
            float xv0 = xp[j * 300 + d0];
            float xv1 = xp[j * 300 + d1];
            a0 += m4 * xv0;
            a1 += m4 * xv1;
        }
        *(f32x4*)&axp[d0 * 16 + g * 4] = a0;
        if (has2) *(f32x4*)&axp[d1 * 16 + g * 4] = a1;
    }
    __syncthreads();
    if (tid < 304) {                       // reduce -> axm[k][4]
        f32x4 s = {0.f, 0.f, 0.f, 0.f};
        if (tid < 300)
            s = *(f32x4*)&axp[tid * 16]     + *(f32x4*)&axp[tid * 16 + 4]
              + *(f32x4*)&axp[tid * 16 + 8] + *(f32x4*)&axp[tid * 16 + 12];
        *(f32x4*)&axm4[tid * 4] = s;
    }
    __syncthreads();

    // ---- phase 2: h partials, group g covers k in [76g, min(76g+76,300)) ----
    {
        f32x4 h0 = {0.f, 0.f, 0.f, 0.f}, h1 = {0.f, 0.f, 0.f, 0.f};
        int kb = g * 76, ke = (g == 3) ? 300 : g * 76 + 76;
#pragma unroll 4
        for (int k = kb; k < ke; ++k) {
            f32x4 m4 = *(const f32x4*)&axm4[k * 4];
            float w0 = Ww[k * 300 + d0];
            float w1 = Ww[k * 300 + d1];
            h0 += m4 * w0;
            h1 += m4 * w1;
        }
        *(f32x4*)&axp[d0 * 16 + g * 4] = h0;
        if (has2) *(f32x4*)&axp[d1 * 16 + g * 4] = h1;
    }
    __syncthreads();

    // ---- h reduce + LN stats ----
    f32x4 hv = {0.f, 0.f, 0.f, 0.f};
    int wv = tid >> 6, lane = tid & 63;
    if (tid < 320) {
        if (tid < 300) {
            hv = *(f32x4*)&axp[tid * 16]     + *(f32x4*)&axp[tid * 16 + 4]
               + *(f32x4*)&axp[tid * 16 + 8] + *(f32x4*)&axp[tid * 16 + 12];
            hv += Wb[tid];
        }
        float s1r[4], s2r[4];
#pragma unroll
        for (int r = 0; r < 4; ++r) { s1r[r] = hv[r]; s2r[r] = hv[r] * hv[r]; }
        for (int off = 32; off; off >>= 1) {
#pragma unroll
            for (int r = 0; r < 4; ++r) {
                s1r[r] += __shfl_down(s1r[r], off);
                s2r[r] += __shfl_down(s2r[r], off);
            }
        }
        if (lane == 0) {
#pragma unroll
            for (int r = 0; r < 4; ++r) { red1[wv * 4 + r] = s1r[r]; red2[wv * 4 + r] = s2r[r]; }
        }
    }
    __syncthreads();
    if (tid < 4) {
        float s1 = 0.f, s2 = 0.f;
#pragma unroll
        for (int w = 0; w < 5; ++w) { s1 += red1[w * 4 + tid]; s2 += red2[w * 4 + tid]; }
        float mean = s1 * (1.0f / 300.0f);
        float var = (s2 - 300.0f * mean * mean) * (1.0f / 299.0f);
        var = fmaxf(var, 0.0f);
        stats[tid * 2] = mean;
        stats[tid * 2 + 1] = 1.0f / (sqrtf(var) + 1e-6f);
    }
    __syncthreads();

    // ---- apply LN + relu -> node_out + srcL ----
    if (tid < 300) {
        float la = lna[tid], lb = lnb[tid];
        f32x4 nv;
#pragma unroll
        for (int r = 0; r < 4; ++r) {
            float v = la * (hv[r] - stats[r * 2]) * stats[r * 2 + 1] + lb;
            v = fmaxf(v, 0.f);
            nv[r] = v;
            node_out[(size_t)(row0 + r) * 300 + tid] = v;
        }
        *(f32x4*)&srcL[(50 + tid) * 4] = nv;
    }
    __syncthreads();

    // ---- phase 3: R1/R2 partials, 10 chunks of 35 over concat K=350 ----
    if (tid < 500) {
        int p = tid / 50, k = tid % 50;
        f32x4 r1a = {0.f, 0.f, 0.f, 0.f}, r2a = {0.f, 0.f, 0.f, 0.f};
        int ib = p * 35;
#pragma unroll 5
        for (int idx = ib; idx < ib + 35; ++idx) {
            f32x4 sv = *(const f32x4*)&srcL[idx * 4];
            float w1, w2;
            if (idx < 50) { w1 = Rw[(50 + idx) * 50 + k]; w2 = Rw[(100 + idx) * 50 + k]; }
            else { int d = idx - 50; w1 = Rw[(150 + d) * 50 + k]; w2 = Rw[(450 + d) * 50 + k]; }
            r1a += sv * w1;
            r2a += sv * w2;
        }
        *(f32x4*)&axp[(p * 50 + k) * 4] = r1a;
        *(f32x4*)&axp[2000 + (p * 50 + k) * 4] = r2a;
    }
    __syncthreads();
    if (tid < 200) {
        int r = tid / 50, k = tid % 50;
        float s1 = 0.f, s2 = rb[k];
#pragma unroll
        for (int p = 0; p < 10; ++p) {
            s1 += axp[(p * 50 + k) * 4 + r];
            s2 += axp[2000 + (p * 50 + k) * 4 + r];
        }
        R1[(size_t)(row0 + r) * 50 + k] = s1;
        R2[(size_t)(row0 + r) * 50 + k] = s2;
    }
}

// ---------------- K2: edge_out = wa·Rw[0:50] (MFMA) + R1[j] + R2[i] ------------
__global__ void __launch_bounds__(256) k_edge(
    const float* __restrict__ wa,
    const float* __restrict__ Rw,
    const float* __restrict__ R1, const float* __restrict__ R2,
    float* __restrict__ eout)
{
    __shared__ __align__(16) unsigned char smem[27648];
    unsigned short* waA  = (unsigned short*)smem;            // 128*72 bf16
    unsigned short* rwBT = (unsigned short*)(smem + 18432);  // 64*72 bf16
    float* outF = (float*)smem;                              // alias: 6400 floats
    int tid = threadIdx.x;
    int bi = blockIdx.x;       // b*128 + i
    int b = bi >> 7;

    for (int idx = tid; idx < 2304; idx += 256) ((unsigned int*)rwBT)[idx] = 0u;
    for (int idx = tid; idx < 1408; idx += 256) {            // zero waA pad e in [50,72)
        int j = idx / 11, c = idx % 11;
        *((unsigned int*)(waA + j * 72 + 50) + c) = 0u;
    }
    __syncthreads();

    const float2* wap = (const float2*)(wa + (size_t)bi * 6400);
    for (int idx = tid; idx < 3200; idx += 256) {
        float2 v = wap[idx];
        int f = idx * 2;
        int j = f / 50, e = f % 50;
        unsigned int pack = (unsigned int)f2bf(v.x) | ((unsigned int)f2bf(v.y) << 16);
        *(unsigned int*)(waA + j * 72 + e) = pack;
    }
    for (int idx = tid; idx < 2500; idx += 256) {            // transpose+cvt Rw[0:50][0:50]
        int e = idx / 50, kk = idx % 50;
        rwBT[kk * 72 + e] = f2bf(Rw[idx]);
    }
    __syncthreads();

    int lane = tid & 63, wv = tid >> 6;
    int q = lane >> 4, lr = lane & 15;
    f32x4 acc[2][4] = {};

#pragma unroll
    for (int ks = 0; ks < 2; ++ks) {
        int e0 = ks * 32 + q * 8;
        bf16x8 a0 = *(const bf16x8*)&waA[(wv * 32 + lr) * 72 + e0];
        bf16x8 a1 = *(const bf16x8*)&waA[(wv * 32 + 16 + lr) * 72 + e0];
#pragma unroll
        for (int nt = 0; nt < 4; ++nt) {
            bf16x8 bb = *(const bf16x8*)&rwBT[(nt * 16 + lr) * 72 + e0];
            acc[0][nt] = __builtin_amdgcn_mfma_f32_16x16x32_bf16(a0, bb, acc[0][nt], 0, 0, 0);
            acc[1][nt] = __builtin_amdgcn_mfma_f32_16x16x32_bf16(a1, bb, acc[1][nt], 0, 0, 0);
        }
    }
    __syncthreads();   // staging LDS dead; alias as outF

    const float* r2p = R2 + (size_t)bi * 50;
#pragma unroll
    for (int nt = 0; nt < 4; ++nt) {
        int kk = nt * 16 + lr;
        if (kk < 50) {
            float r2v = r2p[kk];
#pragma unroll
            for (int mi = 0; mi < 2; ++mi) {
                int jbase = wv * 32 + mi * 16 + q * 4;
#pragma unroll
                for (int r = 0; r < 4; ++r)
                    outF[(jbase + r) * 50 + kk] = acc[mi][nt][r] + r2v;
            }
        }
    }
    __syncthreads();

    const float4* R1b = (const float4*)(R1 + (size_t)b * 6400);
    const float4* L4  = (const float4*)outF;
    float4* op4 = (float4*)(eout + (size_t)bi * 6400);
    for (int f4 = tid; f4 < 1600; f4 += 256) {
        float4 v = L4[f4];
        float4 r = R1b[f4];
        v.x += r.x; v.y += r.y; v.z += r.z; v.w += r.w;
        op4[f4] = v;
    }
}

extern "C" void kernel_launch(void* const* d_in, const int* in_sizes, int n_in,
                              void* d_out, int out_size, void* d_ws, size_t ws_size,
                              hipStream_t stream)
{
    const float* wps = (const float*)d_in[0];
    const float* wa  = (const float*)d_in[1];
    const float* x   = (const float*)d_in[2];
    // d_in[3] self_loop: identity on every channel, folded into k_msum (+1 on diag)
    const float* Ww  = (const float*)d_in[4];
    const float* Wb  = (const float*)d_in[5];
    const float* lna = (const float*)d_in[6];
    const float* lnb = (const float*)d_in[7];
    const float* Rw  = (const float*)d_in[8];
    const float* rb  = (const float*)d_in[9];

    float* R1 = (float*)d_ws;                    // 51200 floats
    float* R2 = ((float*)d_ws) + 51200;          // 51200 floats
    float* M  = ((float*)d_ws) + 102400;         // 131072 floats

    float* node_out = (float*)d_out;             // 307200 floats
    float* edge_out = node_out + 307200;         // 6553600 floats

    k_msum<<<512, 256, 0, stream>>>(wps, M);
    k_node<<<256, 1024, 0, stream>>>(M, wa, x, Ww, Wb, lna, lnb, Rw, rb,
                                     node_out, R1, R2);
    k_edge<<<1024, 256, 0, stream>>>(wa, Rw, R1, R2, edge_out);
}